// Round 9
// baseline (115.069 us; speedup 1.0000x reference)
//
#include <hip/hip_runtime.h>

// LangNN via 16x16x32 bf16 MFMA. B=131072, H=25, A=18.
// Round-9: FUSED {dec(t) + enc(t+1)} loop body — the two cells are mutually
// independent (both consume only he(t), hd(t-1)), so each iteration issues
// 12 MFMAs off the same registers, runs BOTH activation blocks (2x trans ILP),
// and has ONE LDS write+reload point instead of two. Per-wave critical path
// halves vs r8's serial enc->dec chain (r6/r8 both stalled ~35% at ~64% VALUBusy).
// WPB=4/BLK=256: LDS = 26KB frags + 10KB sH = 36864 B -> 4 blocks/CU static.
// Enc step-0 W_ih frags live in REGISTERS (prologue-only) -> no sH alias, no
// mid-kernel barrier. Biases folded via A col k=25 == 1.0 (A/B convention
// identical so k-permutation cancels). Activation: 5 exp2 + 2 rcp per element.
// C/D layout (verified r4-r8): col=lane&15, row=(lane>>4)*4+q.

#define HH 25
#define NSTEP 10
#define AOUT 18
#define WPB 4
#define BLK (WPB * 64)
#define NFRG 26   // 0..7 enc(Wih+Whh) | 8..15 decX | 16..23 decH | 24..25 actor
#define FPAD 40   // 80B row stride: 16B-aligned b128 reads, 2-way conflict (free)
#define LOG2E 1.44269504088896340736f

typedef __attribute__((ext_vector_type(8))) short short8;
typedef __attribute__((ext_vector_type(4))) float f32x4;

__device__ __forceinline__ short f2bf(float x) {   // f32 -> bf16 (RNE), init only
    unsigned u = __float_as_uint(x);
    u += 0x7fffu + ((u >> 16) & 1u);
    return (short)(u >> 16);
}
__device__ __forceinline__ unsigned cvtpk(float lo, float hi) {  // 2xf32 -> packed bf16
    unsigned r;
    asm("v_cvt_pk_bf16_f32 %0, %1, %2" : "=v"(r) : "v"(lo), "v"(hi));
    return r;
}
#if __has_builtin(__builtin_amdgcn_exp2f)
#define EXP2(x) __builtin_amdgcn_exp2f(x)
#else
#define EXP2(x) exp2f(x)
#endif
#define RCP(x) __builtin_amdgcn_rcpf(x)
#define MFMA16(a, b, c) __builtin_amdgcn_mfma_f32_16x16x32_bf16((a), (b), (c), 0, 0, 0)

// one LSTM activation element: acc order i,f,g,o (pre-scaled); updates c, returns h
#define ACT_ELEM(A0, A1, A2, A3, CREF, HOUT)                                   \
    {                                                                          \
        float Ei = EXP2(A0);                                                   \
        float Ef = EXP2(A1);                                                   \
        float Eg = EXP2(A2);                                                   \
        float Eo = EXP2(A3);                                                   \
        float Pf = 1.f + Ef;                                                   \
        float Pig = (1.f + Ei) * (1.f + Eg);                                   \
        float c = fmaf(CREF, Pig, (Eg - 1.f) * Pf) * RCP(Pf * Pig);            \
        CREF = c;                                                              \
        float Ec = EXP2(2.f * LOG2E * c);                                      \
        float Pc = 1.f + Ec;                                                   \
        HOUT = (Pc - 2.f) * RCP(Pc * (1.f + Eo));                              \
    }

__global__ __launch_bounds__(BLK, 4)
void langnn_mfma16(const float* __restrict__ state,
                   const float* __restrict__ Wih_e, const float* __restrict__ Whh_e,
                   const float* __restrict__ bih_e, const float* __restrict__ bhh_e,
                   const float* __restrict__ Wih_d, const float* __restrict__ Whh_d,
                   const float* __restrict__ bih_d, const float* __restrict__ bhh_d,
                   const float* __restrict__ Wact, const float* __restrict__ bact,
                   float* __restrict__ out, int B)
{
    __shared__ __align__(16) short sFrag[NFRG][64][8];      // 26 KB
    __shared__ __align__(16) short sH[2][WPB][16][FPAD];    // 10 KB ([0]=he, [1]=hd)

    const int tid  = threadIdx.x;
    const int lane = tid & 63;
    const int w    = tid >> 6;
    const int r    = lane & 15;    // A-row / C-col lane index
    const int g    = lane >> 4;    // k-group / C row-group

    // ---- build B-fragment table (bias folded into k=25 row) ----
    for (int i = tid; i < NFRG * 64; i += BLK) {
        const int idx = i >> 6, l = i & 63;
        const int lj = l & 15, lg = l >> 4;
        const float *W1 = nullptr, *W2 = nullptr, *B1 = nullptr, *B2 = nullptr;
        int gt = 0, jt, jmax = HH;
        if (idx < 8)       { gt = idx >> 1;        jt = idx & 1; W1 = Wih_e; W2 = Whh_e; B1 = bih_e; B2 = bhh_e; }
        else if (idx < 16) { gt = (idx - 8) >> 1;  jt = idx & 1; W1 = Wih_d; B1 = bih_d; B2 = bhh_d; }
        else if (idx < 24) { gt = (idx - 16) >> 1; jt = idx & 1; W1 = Whh_d; }
        else               { jt = idx - 24;        W1 = Wact;    B1 = bact;  jmax = AOUT; }
        const bool actor = (idx >= 24);
        const float sc = actor ? 1.f : (gt == 2 ? 2.f * LOG2E : -LOG2E);
        const int col = jt * 16 + lj;
        const int nrow = actor ? col : gt * HH + col;
        for (int e = 0; e < 8; ++e) {
            const int k = lg * 8 + e;
            float v = 0.f;
            if (col < jmax) {
                if (k < HH) {
                    v = W1[nrow * HH + k];
                    if (W2) v += W2[nrow * HH + k];
                    v *= sc;
                } else if (k == HH && B1) {
                    v = B1[nrow];
                    if (B2) v += B2[nrow];
                    v *= sc;
                }
            }
            sFrag[idx][l][e] = f2bf(v);
        }
    }
    // ---- init BOTH sH regions: zeros, col 25 = 1.0 (bias lane) ----
    {
        int* z = (int*)sH;
        for (int i = tid; i < 2 * WPB * 16 * (FPAD / 2); i += BLK)
            z[i] = ((i % (FPAD / 2)) == 12) ? 0x3F800000 : 0;   // shorts 24|25 -> 0|1.0
    }
    __syncthreads();

    const int b0 = (blockIdx.x * WPB + w) * 16;
    float* pe = out + (size_t)B * AOUT + (size_t)(b0 + g * 4) * HH + r;

    float ce[2][4], cd[2][4];
    #pragma unroll
    for (int jt = 0; jt < 2; ++jt)
        #pragma unroll
        for (int q = 0; q < 4; ++q) { ce[jt][q] = 0.f; cd[jt][q] = 0.f; }

    // initial A-fragments: encoder x = state; decoder h = 0 (bias lane 1.0)
    short8 aE, aD;
    {
        const float* sp0 = state + (size_t)(b0 + r) * HH;
        #pragma unroll
        for (int e = 0; e < 8; ++e) {
            const int k = g * 8 + e;
            aE[e] = (k < HH) ? f2bf(sp0[k]) : (k == HH ? (short)0x3F80 : (short)0);
            aD[e] = (k == HH) ? (short)0x3F80 : (short)0;
        }
    }

    // ---- enc step 0: W_ih-only frags built into registers (prologue-only) ----
    {
        short8 W0f[8];
        #pragma unroll
        for (int gt = 0; gt < 4; ++gt) {
            const float sc = (gt == 2 ? 2.f * LOG2E : -LOG2E);
            #pragma unroll
            for (int jt = 0; jt < 2; ++jt) {
                const int col = jt * 16 + r;
                short8 v8;
                #pragma unroll
                for (int e = 0; e < 8; ++e) {
                    const int k = g * 8 + e;
                    float v = 0.f;
                    if (col < HH) {
                        if (k < HH)       v = Wih_e[(gt * HH + col) * HH + k] * sc;
                        else if (k == HH) v = (bih_e[gt * HH + col] + bhh_e[gt * HH + col]) * sc;
                    }
                    v8[e] = f2bf(v);
                }
                W0f[gt * 2 + jt] = v8;
            }
        }
        #pragma unroll
        for (int jt = 0; jt < 2; ++jt) {
            f32x4 acc[4];
            #pragma unroll
            for (int gt = 0; gt < 4; ++gt) {
                f32x4 z; z[0] = z[1] = z[2] = z[3] = 0.f;
                acc[gt] = MFMA16(aE, W0f[gt * 2 + jt], z);
            }
            float hv[4];
            #pragma unroll
            for (int q = 0; q < 4; ++q)
                ACT_ELEM(acc[0][q], acc[1][q], acc[2][q], acc[3][q], ce[jt][q], hv[q]);
            if (jt == 0 || r < 9) {
                float* p = pe + jt * 16;
                p[0] = hv[0]; p[HH] = hv[1]; p[2 * HH] = hv[2]; p[3 * HH] = hv[3];
                unsigned p01 = cvtpk(hv[0], hv[1]), p23 = cvtpk(hv[2], hv[3]);
                short* sp = &sH[0][w][g * 4][jt * 16 + r];
                sp[0]        = (short)p01;
                sp[FPAD]     = (short)(p01 >> 16);
                sp[2 * FPAD] = (short)p23;
                sp[3 * FPAD] = (short)(p23 >> 16);
            }
        }
        aE = *(const short8*)&sH[0][w][r][g * 8];
        pe += (size_t)B * HH;
    }

    // ---- fused loop: iteration t computes dec(t) AND enc(t+1), both off he(t) ----
    #pragma unroll 1
    for (int t = 0; t < NSTEP - 1; ++t) {
        #pragma unroll
        for (int jt = 0; jt < 2; ++jt) {
            f32x4 accD[4], accE[4];
            #pragma unroll
            for (int gt = 0; gt < 4; ++gt) {
                short8 Bx = *(const short8*)&sFrag[8 + gt * 2 + jt][lane][0];
                short8 Bh = *(const short8*)&sFrag[16 + gt * 2 + jt][lane][0];
                short8 Be = *(const short8*)&sFrag[gt * 2 + jt][lane][0];
                f32x4 z; z[0] = z[1] = z[2] = z[3] = 0.f;
                accD[gt] = MFMA16(aD, Bh, MFMA16(aE, Bx, z));
                accE[gt] = MFMA16(aE, Be, z);
            }
            float hvD[4], hvE[4];
            #pragma unroll
            for (int q = 0; q < 4; ++q) {
                ACT_ELEM(accD[0][q], accD[1][q], accD[2][q], accD[3][q], cd[jt][q], hvD[q]);
                ACT_ELEM(accE[0][q], accE[1][q], accE[2][q], accE[3][q], ce[jt][q], hvE[q]);
            }
            if (jt == 0 || r < 9) {
                float* p = pe + jt * 16;
                p[0] = hvE[0]; p[HH] = hvE[1]; p[2 * HH] = hvE[2]; p[3 * HH] = hvE[3];
                unsigned d01 = cvtpk(hvD[0], hvD[1]), d23 = cvtpk(hvD[2], hvD[3]);
                unsigned e01 = cvtpk(hvE[0], hvE[1]), e23 = cvtpk(hvE[2], hvE[3]);
                short* spD = &sH[1][w][g * 4][jt * 16 + r];
                short* spE = &sH[0][w][g * 4][jt * 16 + r];
                spD[0]        = (short)d01;
                spD[FPAD]     = (short)(d01 >> 16);
                spD[2 * FPAD] = (short)d23;
                spD[3 * FPAD] = (short)(d23 >> 16);
                spE[0]        = (short)e01;
                spE[FPAD]     = (short)(e01 >> 16);
                spE[2 * FPAD] = (short)e23;
                spE[3 * FPAD] = (short)(e23 >> 16);
            }
        }
        aE = *(const short8*)&sH[0][w][r][g * 8];   // he(t+1)
        aD = *(const short8*)&sH[1][w][r][g * 8];   // hd(t)
        pe += (size_t)B * HH;
    }

    // ---- dec step 9 (no paired encoder) ----
    #pragma unroll
    for (int jt = 0; jt < 2; ++jt) {
        f32x4 acc[4];
        #pragma unroll
        for (int gt = 0; gt < 4; ++gt) {
            short8 Bx = *(const short8*)&sFrag[8 + gt * 2 + jt][lane][0];
            short8 Bh = *(const short8*)&sFrag[16 + gt * 2 + jt][lane][0];
            f32x4 z; z[0] = z[1] = z[2] = z[3] = 0.f;
            acc[gt] = MFMA16(aD, Bh, MFMA16(aE, Bx, z));
        }
        float hv[4];
        #pragma unroll
        for (int q = 0; q < 4; ++q)
            ACT_ELEM(acc[0][q], acc[1][q], acc[2][q], acc[3][q], cd[jt][q], hv[q]);
        if (jt == 0 || r < 9) {
            unsigned p01 = cvtpk(hv[0], hv[1]), p23 = cvtpk(hv[2], hv[3]);
            short* sp = &sH[1][w][g * 4][jt * 16 + r];
            sp[0]        = (short)p01;
            sp[FPAD]     = (short)(p01 >> 16);
            sp[2 * FPAD] = (short)p23;
            sp[3 * FPAD] = (short)(p23 >> 16);
        }
    }
    aD = *(const short8*)&sH[1][w][r][g * 8];       // hd(9)

    // ---- actor head (bias via k=25) ----
    #pragma unroll
    for (int jt = 0; jt < 2; ++jt) {
        short8 Bf = *(const short8*)&sFrag[24 + jt][lane][0];
        f32x4 z; z[0] = z[1] = z[2] = z[3] = 0.f;
        f32x4 o = MFMA16(aD, Bf, z);
        if (jt == 0 || r < 2) {
            float* p = out + (size_t)(b0 + g * 4) * AOUT + jt * 16 + r;
            p[0] = o[0]; p[AOUT] = o[1]; p[2 * AOUT] = o[2]; p[3 * AOUT] = o[3];
        }
    }
}

extern "C" void kernel_launch(void* const* d_in, const int* in_sizes, int n_in,
                              void* d_out, int out_size, void* d_ws, size_t ws_size,
                              hipStream_t stream) {
    const float* state = (const float*)d_in[0];
    const float* Wih_e = (const float*)d_in[1];
    const float* Whh_e = (const float*)d_in[2];
    const float* bih_e = (const float*)d_in[3];
    const float* bhh_e = (const float*)d_in[4];
    const float* Wih_d = (const float*)d_in[5];
    const float* Whh_d = (const float*)d_in[6];
    const float* bih_d = (const float*)d_in[7];
    const float* bhh_d = (const float*)d_in[8];
    const float* Wact  = (const float*)d_in[9];
    const float* bact  = (const float*)d_in[10];

    int B = in_sizes[0] / HH;
    int grid = B / (WPB * 16);   // 131072/64 = 2048 blocks

    hipLaunchKernelGGL(langnn_mfma16, dim3(grid), dim3(BLK), 0, stream,
                       state, Wih_e, Whh_e, bih_e, bhh_e,
                       Wih_d, Whh_d, bih_d, bhh_d, Wact, bact,
                       (float*)d_out, B);
}

// Round 10
// 110.057 us; speedup vs baseline: 1.0455x; 1.0455x over previous
//
#include <hip/hip_runtime.h>

// LangNN via SWAPPED-operand 16x16x32 bf16 MFMA. B=131072, H=25, A=18.
// Round-10: gates computed as W·h^T (A=weights from LDS, B=h in registers).
// Gates padded to 32 rows each -> 8 M-tiles/cell. C/D layout (verified r4-r9:
// col=lane&15, row=(lane>>4)*4+q) => lane (r,g) gets gate values for batch
// col r at features {g*4+q, 16+g*4+q}. With the shared A/B k-slot bijection
// phi(g,e) = e<4 ? g*4+e : 16+g*4+(e-4), the packed bf16 activation output
// IS the next step's B-fragment: the h recurrence never touches LDS.
// No sH, no per-step lgkmcnt round-trip, one barrier total -> waves drift
// freely and fill the trans pipe (r6-r9 convoy-locked at ~64% VALUBusy).
// Bias folded via h feature 31 == 1.0 (g==3 lane patches slot e=7 at pack);
// padding features 25..30 carry bounded garbage x zero weight columns.

#define HH 25
#define NSTEP 10
#define AOUT 18
#define WPB 4
#define BLK (WPB * 64)
#define NFRG 26   // 0..7 enc(Wih+Whh) | 8..15 decX | 16..23 decH | 24..25 actor
#define LOG2E 1.44269504088896340736f

typedef __attribute__((ext_vector_type(8))) short short8;
typedef __attribute__((ext_vector_type(4))) float f32x4;
typedef __attribute__((ext_vector_type(4))) unsigned u32x4;

__device__ __forceinline__ short f2bf(float x) {   // f32 -> bf16 (RNE)
    unsigned u = __float_as_uint(x);
    u += 0x7fffu + ((u >> 16) & 1u);
    return (short)(u >> 16);
}
__device__ __forceinline__ unsigned cvtpk(float lo, float hi) {  // 2xf32 -> packed bf16
    unsigned rr;
    asm("v_cvt_pk_bf16_f32 %0, %1, %2" : "=v"(rr) : "v"(lo), "v"(hi));
    return rr;
}
#if __has_builtin(__builtin_amdgcn_exp2f)
#define EXP2(x) __builtin_amdgcn_exp2f(x)
#else
#define EXP2(x) exp2f(x)
#endif
#define RCP(x) __builtin_amdgcn_rcpf(x)
#define MFMA16(a, b, c) __builtin_amdgcn_mfma_f32_16x16x32_bf16((a), (b), (c), 0, 0, 0)

// one LSTM activation element: gates i,f,g,o pre-scaled by -log2e/+2log2e
#define ACT_ELEM(A0, A1, A2, A3, CREF, HOUT)                                   \
    {                                                                          \
        float Ei = EXP2(A0);                                                   \
        float Ef = EXP2(A1);                                                   \
        float Eg = EXP2(A2);                                                   \
        float Eo = EXP2(A3);                                                   \
        float Pf = 1.f + Ef;                                                   \
        float Pig = (1.f + Ei) * (1.f + Eg);                                   \
        float c = fmaf(CREF, Pig, (Eg - 1.f) * Pf) * RCP(Pf * Pig);            \
        CREF = c;                                                              \
        float Ec = EXP2(2.f * LOG2E * c);                                      \
        float Pc = 1.f + Ec;                                                   \
        HOUT = (Pc - 2.f) * RCP(Pc * (1.f + Eo));                              \
    }

__global__ __launch_bounds__(BLK, 4)
void langnn_swap(const float* __restrict__ state,
                 const float* __restrict__ Wih_e, const float* __restrict__ Whh_e,
                 const float* __restrict__ bih_e, const float* __restrict__ bhh_e,
                 const float* __restrict__ Wih_d, const float* __restrict__ Whh_d,
                 const float* __restrict__ bih_d, const float* __restrict__ bhh_d,
                 const float* __restrict__ Wact, const float* __restrict__ bact,
                 float* __restrict__ out, int B)
{
    __shared__ __align__(16) short sFrag[NFRG][64][8];   // 26 KB, read-only after init

    const int tid  = threadIdx.x;
    const int lane = tid & 63;
    const int w    = tid >> 6;
    const int r    = lane & 15;    // B col (batch) / A row-within-tile
    const int g    = lane >> 4;    // k-chunk / C row-group

    // ---- build A-fragment (weight) table; bias in k-slot feature 31 ----
    for (int i = tid; i < NFRG * 64; i += BLK) {
        const int idx = i >> 6, l = i & 63;
        const int lj = l & 15, lg = l >> 4;
        const float *W1 = nullptr, *W2 = nullptr, *B1 = nullptr, *B2 = nullptr;
        int gt = 0, hf, rmax = HH;
        if (idx < 8)       { gt = idx >> 1;        hf = idx & 1; W1 = Wih_e; W2 = Whh_e; B1 = bih_e; B2 = bhh_e; }
        else if (idx < 16) { gt = (idx - 8) >> 1;  hf = idx & 1; W1 = Wih_d; B1 = bih_d; B2 = bhh_d; }
        else if (idx < 24) { gt = (idx - 16) >> 1; hf = idx & 1; W1 = Whh_d; }
        else               { hf = idx - 24;        W1 = Wact;    B1 = bact;  rmax = AOUT; }
        const bool actor = (idx >= 24);
        const float sc = actor ? 1.f : (gt == 2 ? 2.f * LOG2E : -LOG2E);
        const int row  = hf * 16 + lj;                 // output feature row of this tile
        const int nrow = actor ? row : gt * HH + row;  // row in the weight matrix
        for (int e = 0; e < 8; ++e) {
            const int k = (e < 4) ? lg * 4 + e : 16 + lg * 4 + (e - 4);   // phi(lg,e)
            float v = 0.f;
            if (row < rmax) {
                if (k < HH) {
                    v = W1[nrow * HH + k];
                    if (W2) v += W2[nrow * HH + k];
                    v *= sc;
                } else if (k == 31 && B1) {
                    v = B1[nrow];
                    if (B2) v += B2[nrow];
                    v *= sc;
                }
            }
            sFrag[idx][l][e] = f2bf(v);
        }
    }
    __syncthreads();   // the only barrier

    const int b0 = (blockIdx.x * WPB + w) * 16;
    float* encBase = out + (size_t)B * AOUT + (size_t)(b0 + r) * HH;

    float ce[2][4], cd[2][4];
    #pragma unroll
    for (int hf = 0; hf < 2; ++hf)
        #pragma unroll
        for (int q = 0; q < 4; ++q) { ce[hf][q] = 0.f; cd[hf][q] = 0.f; }

    // initial B-fragments: hE = state (feature 31 slot = 1.0 for bias), hD = 0
    short8 hE, hD;
    {
        const float* sp = state + (size_t)(b0 + r) * HH;
        #pragma unroll
        for (int e = 0; e < 8; ++e) {
            const int k = (e < 4) ? g * 4 + e : 16 + g * 4 + (e - 4);
            hE[e] = (k < HH) ? f2bf(sp[k]) : (k == 31 ? (short)0x3F80 : (short)0);
            hD[e] = (k == 31) ? (short)0x3F80 : (short)0;
        }
    }

    auto actCell = [&](f32x4 (&acc)[8], float (&cc)[2][4], float (&hv)[2][4]) {
        #pragma unroll
        for (int hf = 0; hf < 2; ++hf)
            #pragma unroll
            for (int q = 0; q < 4; ++q)
                ACT_ELEM(acc[0 + hf][q], acc[2 + hf][q], acc[4 + hf][q], acc[6 + hf][q],
                         cc[hf][q], hv[hf][q]);
    };
    auto packH = [&](float (&hv)[2][4]) -> short8 {
        union { u32x4 d; short8 s; } u;
        u.d[0] = cvtpk(hv[0][0], hv[0][1]);
        u.d[1] = cvtpk(hv[0][2], hv[0][3]);
        u.d[2] = cvtpk(hv[1][0], hv[1][1]);
        u.d[3] = cvtpk(hv[1][2], (g == 3) ? 1.0f : hv[1][3]);   // feature 31 == 1.0
        return u.s;
    };
    auto storeEnc = [&](int t, float (&hv)[2][4]) {
        float* p = encBase + (size_t)t * B * HH;
        #pragma unroll
        for (int q = 0; q < 4; ++q) p[g * 4 + q] = hv[0][q];          // features 0..15
        #pragma unroll
        for (int q = 0; q < 4; ++q)
            if (g * 4 + q < 9) p[16 + g * 4 + q] = hv[1][q];          // features 16..24
    };

    // ---- enc step 0: W_ih-only frags built on the fly from global (L2-warm) ----
    {
        f32x4 acc[8];
        #pragma unroll
        for (int idx = 0; idx < 8; ++idx) {
            const int gt = idx >> 1, hf = idx & 1;
            const float sc = (gt == 2) ? 2.f * LOG2E : -LOG2E;
            const int row = hf * 16 + r;
            short8 Wf;
            #pragma unroll
            for (int e = 0; e < 8; ++e) {
                const int k = (e < 4) ? g * 4 + e : 16 + g * 4 + (e - 4);
                float v = 0.f;
                if (row < HH) {
                    if (k < HH)       v = Wih_e[(gt * HH + row) * HH + k] * sc;
                    else if (k == 31) v = (bih_e[gt * HH + row] + bhh_e[gt * HH + row]) * sc;
                }
                Wf[e] = f2bf(v);
            }
            f32x4 z; z[0] = z[1] = z[2] = z[3] = 0.f;
            acc[idx] = MFMA16(Wf, hE, z);
        }
        float hv[2][4];
        actCell(acc, ce, hv);
        storeEnc(0, hv);
        hE = packH(hv);
    }

    auto decCell = [&]() {
        f32x4 acc[8];
        #pragma unroll
        for (int idx = 0; idx < 8; ++idx) {
            short8 Wx = *(const short8*)&sFrag[8 + idx][lane][0];
            short8 Wh = *(const short8*)&sFrag[16 + idx][lane][0];
            f32x4 z; z[0] = z[1] = z[2] = z[3] = 0.f;
            acc[idx] = MFMA16(Wh, hD, MFMA16(Wx, hE, z));
        }
        float hv[2][4];
        actCell(acc, cd, hv);
        hD = packH(hv);
    };
    auto encCell = [&](int t) {
        f32x4 acc[8];
        #pragma unroll
        for (int idx = 0; idx < 8; ++idx) {
            short8 Wf = *(const short8*)&sFrag[idx][lane][0];
            f32x4 z; z[0] = z[1] = z[2] = z[3] = 0.f;
            acc[idx] = MFMA16(Wf, hE, z);
        }
        float hv[2][4];
        actCell(acc, ce, hv);
        storeEnc(t, hv);
        hE = packH(hv);
    };

    #pragma unroll 1
    for (int t = 0; t < NSTEP - 1; ++t) {
        decCell();        // dec(t): reads hE(t), hD(t-1)
        encCell(t + 1);   // enc(t+1): reads hE(t), then overwrites hE
    }
    decCell();            // dec step 9

    // ---- actor head (hD = hd(9); bias via feature-31 slot) ----
    {
        short8 W0 = *(const short8*)&sFrag[24][lane][0];
        short8 W1 = *(const short8*)&sFrag[25][lane][0];
        f32x4 z; z[0] = z[1] = z[2] = z[3] = 0.f;
        f32x4 a0 = MFMA16(W0, hD, z);
        f32x4 a1 = MFMA16(W1, hD, z);
        float* p = out + (size_t)(b0 + r) * AOUT;
        #pragma unroll
        for (int q = 0; q < 4; ++q) p[g * 4 + q] = a0[q];             // rows 0..15
        #pragma unroll
        for (int q = 0; q < 4; ++q)
            if (16 + g * 4 + q < AOUT) p[16 + g * 4 + q] = a1[q];     // rows 16..17
    }
}

extern "C" void kernel_launch(void* const* d_in, const int* in_sizes, int n_in,
                              void* d_out, int out_size, void* d_ws, size_t ws_size,
                              hipStream_t stream) {
    const float* state = (const float*)d_in[0];
    const float* Wih_e = (const float*)d_in[1];
    const float* Whh_e = (const float*)d_in[2];
    const float* bih_e = (const float*)d_in[3];
    const float* bhh_e = (const float*)d_in[4];
    const float* Wih_d = (const float*)d_in[5];
    const float* Whh_d = (const float*)d_in[6];
    const float* bih_d = (const float*)d_in[7];
    const float* bhh_d = (const float*)d_in[8];
    const float* Wact  = (const float*)d_in[9];
    const float* bact  = (const float*)d_in[10];

    int B = in_sizes[0] / HH;
    int grid = B / (WPB * 16);   // 131072/64 = 2048 blocks

    hipLaunchKernelGGL(langnn_swap, dim3(grid), dim3(BLK), 0, stream,
                       state, Wih_e, Whh_e, bih_e, bhh_e,
                       Wih_d, Whh_d, bih_d, bhh_d, Wact, bact,
                       (float*)d_out, B);
}

// Round 11
// 101.766 us; speedup vs baseline: 1.1307x; 1.0815x over previous
//
#include <hip/hip_runtime.h>

// LangNN via SWAPPED-operand 16x16x32 bf16 MFMA. B=131072, H=25, A=18.
// Round-11: r10's register-resident recurrence + TWO independent batch groups
// per wave (32 rows/wave). r6-r10 plateaued at ~60% VALUBusy because all waves
// run identical code and phase-lock on the trans/matrix pipes; two independent
// groups interleave MFMA/trans/VALU *within* each wave, hiding the per-step
// dependency chain structurally. One sFrag read feeds both groups' MFMAs.
// Cells processed in two hf-phases to cap the acc watermark (32 regs).
// Recurrence stays in registers: packed bf16 activation output IS the next
// B-fragment under the shared k-slot bijection phi(g,e)=e<4?g*4+e:16+g*4+e-4.
// Bias folded via h feature 31 == 1.0. C/D layout (verified r4-r10):
// col=lane&15, row=(lane>>4)*4+q.

#define HH 25
#define NSTEP 10
#define AOUT 18
#define WPB 4
#define BLK (WPB * 64)
#define NG 2      // independent batch groups per wave
#define NFRG 26   // 0..7 enc(Wih+Whh) | 8..15 decX | 16..23 decH | 24..25 actor
#define LOG2E 1.44269504088896340736f

typedef __attribute__((ext_vector_type(8))) short short8;
typedef __attribute__((ext_vector_type(4))) float f32x4;
typedef __attribute__((ext_vector_type(4))) unsigned u32x4;
typedef float f32x4u __attribute__((ext_vector_type(4), aligned(4)));  // 4B-aligned vec store

__device__ __forceinline__ short f2bf(float x) {   // f32 -> bf16 (RNE)
    unsigned u = __float_as_uint(x);
    u += 0x7fffu + ((u >> 16) & 1u);
    return (short)(u >> 16);
}
__device__ __forceinline__ unsigned cvtpk(float lo, float hi) {  // 2xf32 -> packed bf16
    unsigned rr;
    asm("v_cvt_pk_bf16_f32 %0, %1, %2" : "=v"(rr) : "v"(lo), "v"(hi));
    return rr;
}
#if __has_builtin(__builtin_amdgcn_exp2f)
#define EXP2(x) __builtin_amdgcn_exp2f(x)
#else
#define EXP2(x) exp2f(x)
#endif
#define RCP(x) __builtin_amdgcn_rcpf(x)
#define MFMA16(a, b, c) __builtin_amdgcn_mfma_f32_16x16x32_bf16((a), (b), (c), 0, 0, 0)

// one LSTM activation element: gates i,f,g,o pre-scaled by -log2e/+2log2e
#define ACT_ELEM(A0, A1, A2, A3, CREF, HOUT)                                   \
    {                                                                          \
        float Ei = EXP2(A0);                                                   \
        float Ef = EXP2(A1);                                                   \
        float Eg = EXP2(A2);                                                   \
        float Eo = EXP2(A3);                                                   \
        float Pf = 1.f + Ef;                                                   \
        float Pig = (1.f + Ei) * (1.f + Eg);                                   \
        float c = fmaf(CREF, Pig, (Eg - 1.f) * Pf) * RCP(Pf * Pig);            \
        CREF = c;                                                              \
        float Ec = EXP2(2.f * LOG2E * c);                                      \
        float Pc = 1.f + Ec;                                                   \
        HOUT = (Pc - 2.f) * RCP(Pc * (1.f + Eo));                              \
    }

__global__ __launch_bounds__(BLK, 3)
void langnn_swap2(const float* __restrict__ state,
                  const float* __restrict__ Wih_e, const float* __restrict__ Whh_e,
                  const float* __restrict__ bih_e, const float* __restrict__ bhh_e,
                  const float* __restrict__ Wih_d, const float* __restrict__ Whh_d,
                  const float* __restrict__ bih_d, const float* __restrict__ bhh_d,
                  const float* __restrict__ Wact, const float* __restrict__ bact,
                  float* __restrict__ out, int B)
{
    __shared__ __align__(16) short sFrag[NFRG][64][8];   // 26 KB, read-only after init

    const int tid  = threadIdx.x;
    const int lane = tid & 63;
    const int w    = tid >> 6;
    const int r    = lane & 15;    // B col (batch) / A row-within-tile
    const int g    = lane >> 4;    // k-chunk / C row-group

    // ---- build A-fragment (weight) table; bias in k-slot feature 31 ----
    for (int i = tid; i < NFRG * 64; i += BLK) {
        const int idx = i >> 6, l = i & 63;
        const int lj = l & 15, lg = l >> 4;
        const float *W1 = nullptr, *W2 = nullptr, *B1 = nullptr, *B2 = nullptr;
        int gt = 0, hf, rmax = HH;
        if (idx < 8)       { gt = idx >> 1;        hf = idx & 1; W1 = Wih_e; W2 = Whh_e; B1 = bih_e; B2 = bhh_e; }
        else if (idx < 16) { gt = (idx - 8) >> 1;  hf = idx & 1; W1 = Wih_d; B1 = bih_d; B2 = bhh_d; }
        else if (idx < 24) { gt = (idx - 16) >> 1; hf = idx & 1; W1 = Whh_d; }
        else               { hf = idx - 24;        W1 = Wact;    B1 = bact;  rmax = AOUT; }
        const bool actor = (idx >= 24);
        const float sc = actor ? 1.f : (gt == 2 ? 2.f * LOG2E : -LOG2E);
        const int row  = hf * 16 + lj;
        const int nrow = actor ? row : gt * HH + row;
        for (int e = 0; e < 8; ++e) {
            const int k = (e < 4) ? lg * 4 + e : 16 + lg * 4 + (e - 4);   // phi(lg,e)
            float v = 0.f;
            if (row < rmax) {
                if (k < HH) {
                    v = W1[nrow * HH + k];
                    if (W2) v += W2[nrow * HH + k];
                    v *= sc;
                } else if (k == 31 && B1) {
                    v = B1[nrow];
                    if (B2) v += B2[nrow];
                    v *= sc;
                }
            }
            sFrag[idx][l][e] = f2bf(v);
        }
    }
    __syncthreads();   // the only barrier

    const int b0 = (blockIdx.x * WPB + w) * (NG * 16);

    float ce[NG][2][4], cd[NG][2][4];
    #pragma unroll
    for (int u = 0; u < NG; ++u)
        #pragma unroll
        for (int hf = 0; hf < 2; ++hf)
            #pragma unroll
            for (int q = 0; q < 4; ++q) { ce[u][hf][q] = 0.f; cd[u][hf][q] = 0.f; }

    // initial B-fragments: hE = state (feature-31 slot = 1.0), hD = 0
    short8 hE[NG], hD[NG];
    #pragma unroll
    for (int u = 0; u < NG; ++u) {
        const float* sp = state + (size_t)(b0 + u * 16 + r) * HH;
        #pragma unroll
        for (int e = 0; e < 8; ++e) {
            const int k = (e < 4) ? g * 4 + e : 16 + g * 4 + (e - 4);
            hE[u][e] = (k < HH) ? f2bf(sp[k]) : (k == 31 ? (short)0x3F80 : (short)0);
            hD[u][e] = (k == 31) ? (short)0x3F80 : (short)0;
        }
    }

    auto packH = [&](float (&hv)[2][4]) -> short8 {
        union { u32x4 d; short8 s; } un;
        un.d[0] = cvtpk(hv[0][0], hv[0][1]);
        un.d[1] = cvtpk(hv[0][2], hv[0][3]);
        un.d[2] = cvtpk(hv[1][0], hv[1][1]);
        un.d[3] = cvtpk(hv[1][2], (g == 3) ? 1.0f : hv[1][3]);   // feature 31 == 1.0
        return un.s;
    };
    // store one hf-slice of enc h for group u at step t
    auto storeEncHF = [&](int t, int u, int hf, float (&hv4)[4]) {
        float* p = out + (size_t)B * AOUT + (size_t)t * B * HH + (size_t)(b0 + u * 16 + r) * HH;
        if (hf == 0) {
            f32x4u v; v[0] = hv4[0]; v[1] = hv4[1]; v[2] = hv4[2]; v[3] = hv4[3];
            *(f32x4u*)(p + g * 4) = v;                       // features 0..15
        } else {
            if (g < 2) {
                f32x4u v; v[0] = hv4[0]; v[1] = hv4[1]; v[2] = hv4[2]; v[3] = hv4[3];
                *(f32x4u*)(p + 16 + g * 4) = v;              // features 16..23
            } else if (g == 2) {
                p[24] = hv4[0];                              // feature 24
            }
        }
    };

    // ---- enc step 0: W_ih-only frags built on the fly from global (L2-warm) ----
    {
        float hvE[NG][2][4];
        #pragma unroll
        for (int hf = 0; hf < 2; ++hf) {
            f32x4 acc[NG][4];
            #pragma unroll
            for (int gt = 0; gt < 4; ++gt) {
                const float sc = (gt == 2) ? 2.f * LOG2E : -LOG2E;
                const int row = hf * 16 + r;
                short8 Wf;
                #pragma unroll
                for (int e = 0; e < 8; ++e) {
                    const int k = (e < 4) ? g * 4 + e : 16 + g * 4 + (e - 4);
                    float v = 0.f;
                    if (row < HH) {
                        if (k < HH)       v = Wih_e[(gt * HH + row) * HH + k] * sc;
                        else if (k == 31) v = (bih_e[gt * HH + row] + bhh_e[gt * HH + row]) * sc;
                    }
                    Wf[e] = f2bf(v);
                }
                f32x4 z; z[0] = z[1] = z[2] = z[3] = 0.f;
                #pragma unroll
                for (int u = 0; u < NG; ++u) acc[u][gt] = MFMA16(Wf, hE[u], z);
            }
            #pragma unroll
            for (int u = 0; u < NG; ++u) {
                #pragma unroll
                for (int q = 0; q < 4; ++q)
                    ACT_ELEM(acc[u][0][q], acc[u][1][q], acc[u][2][q], acc[u][3][q],
                             ce[u][hf][q], hvE[u][hf][q]);
                storeEncHF(0, u, hf, hvE[u][hf]);
            }
        }
        #pragma unroll
        for (int u = 0; u < NG; ++u) hE[u] = packH(hvE[u]);
    }

    auto decCell = [&]() {
        float hvD[NG][2][4];
        #pragma unroll
        for (int hf = 0; hf < 2; ++hf) {
            f32x4 acc[NG][4];
            #pragma unroll
            for (int gt = 0; gt < 4; ++gt) {
                short8 Wx = *(const short8*)&sFrag[8 + gt * 2 + hf][lane][0];
                short8 Wh = *(const short8*)&sFrag[16 + gt * 2 + hf][lane][0];
                f32x4 z; z[0] = z[1] = z[2] = z[3] = 0.f;
                #pragma unroll
                for (int u = 0; u < NG; ++u)
                    acc[u][gt] = MFMA16(Wh, hD[u], MFMA16(Wx, hE[u], z));
            }
            #pragma unroll
            for (int u = 0; u < NG; ++u)
                #pragma unroll
                for (int q = 0; q < 4; ++q)
                    ACT_ELEM(acc[u][0][q], acc[u][1][q], acc[u][2][q], acc[u][3][q],
                             cd[u][hf][q], hvD[u][hf][q]);
        }
        #pragma unroll
        for (int u = 0; u < NG; ++u) hD[u] = packH(hvD[u]);
    };
    auto encCell = [&](int t) {
        float hvE[NG][2][4];
        #pragma unroll
        for (int hf = 0; hf < 2; ++hf) {
            f32x4 acc[NG][4];
            #pragma unroll
            for (int gt = 0; gt < 4; ++gt) {
                short8 Wf = *(const short8*)&sFrag[gt * 2 + hf][lane][0];
                f32x4 z; z[0] = z[1] = z[2] = z[3] = 0.f;
                #pragma unroll
                for (int u = 0; u < NG; ++u) acc[u][gt] = MFMA16(Wf, hE[u], z);
            }
            #pragma unroll
            for (int u = 0; u < NG; ++u) {
                #pragma unroll
                for (int q = 0; q < 4; ++q)
                    ACT_ELEM(acc[u][0][q], acc[u][1][q], acc[u][2][q], acc[u][3][q],
                             ce[u][hf][q], hvE[u][hf][q]);
                storeEncHF(t, u, hf, hvE[u][hf]);
            }
        }
        #pragma unroll
        for (int u = 0; u < NG; ++u) hE[u] = packH(hvE[u]);
    };

    #pragma unroll 1
    for (int t = 0; t < NSTEP - 1; ++t) {
        decCell();        // dec(t): reads hE(t), hD(t-1)
        encCell(t + 1);   // enc(t+1): reads hE(t), then replaces hE
    }
    decCell();            // dec step 9

    // ---- actor head (hD = hd(9); bias via feature-31 slot) ----
    {
        short8 W0 = *(const short8*)&sFrag[24][lane][0];
        short8 W1 = *(const short8*)&sFrag[25][lane][0];
        #pragma unroll
        for (int u = 0; u < NG; ++u) {
            f32x4 z; z[0] = z[1] = z[2] = z[3] = 0.f;
            f32x4 a0 = MFMA16(W0, hD[u], z);
            f32x4 a1 = MFMA16(W1, hD[u], z);
            float* p = out + (size_t)(b0 + u * 16 + r) * AOUT;
            f32x4u v; v[0] = a0[0]; v[1] = a0[1]; v[2] = a0[2]; v[3] = a0[3];
            *(f32x4u*)(p + g * 4) = v;                       // rows 0..15
            if (g == 0) { p[16] = a1[0]; p[17] = a1[1]; }    // rows 16..17
        }
    }
}

extern "C" void kernel_launch(void* const* d_in, const int* in_sizes, int n_in,
                              void* d_out, int out_size, void* d_ws, size_t ws_size,
                              hipStream_t stream) {
    const float* state = (const float*)d_in[0];
    const float* Wih_e = (const float*)d_in[1];
    const float* Whh_e = (const float*)d_in[2];
    const float* bih_e = (const float*)d_in[3];
    const float* bhh_e = (const float*)d_in[4];
    const float* Wih_d = (const float*)d_in[5];
    const float* Whh_d = (const float*)d_in[6];
    const float* bih_d = (const float*)d_in[7];
    const float* bhh_d = (const float*)d_in[8];
    const float* Wact  = (const float*)d_in[9];
    const float* bact  = (const float*)d_in[10];

    int B = in_sizes[0] / HH;
    int grid = B / (WPB * NG * 16);   // 131072/128 = 1024 blocks

    hipLaunchKernelGGL(langnn_swap2, dim3(grid), dim3(BLK), 0, stream,
                       state, Wih_e, Whh_e, bih_e, bhh_e,
                       Wih_d, Whh_d, bih_d, bhh_d, Wact, bact,
                       (float*)d_out, B);
}